// Round 1
// baseline (2113.755 us; speedup 1.0000x reference)
//
#include <hip/hip_runtime.h>

#define KAPPA 0.95f

// ---------- bf16 helpers (manual, round-to-nearest-even) ----------
static __device__ inline unsigned short f2bf(float f) {
    unsigned int u = __float_as_uint(f);
    unsigned int rounding = 0x7fffu + ((u >> 16) & 1u);
    u += rounding;
    return (unsigned short)(u >> 16);
}

// ---------- 1. proj_norm_inf on W_conv: one thread per row ----------
__global__ __launch_bounds__(128) void proj_kernel(const float* __restrict__ W,
                                                   float* __restrict__ WpT) {
    int r = threadIdx.x;  // 0..127
    float a[128], u[128], css[128];
    float rowsum = 0.f;
    for (int j = 0; j < 128; ++j) {
        float w = W[r * 128 + j];
        a[j] = fabsf(w);
        rowsum += a[j];
    }
    if (rowsum > KAPPA) {
        for (int j = 0; j < 128; ++j) u[j] = a[j];
        // insertion sort descending
        for (int i = 1; i < 128; ++i) {
            float key = u[i];
            int j = i - 1;
            while (j >= 0 && u[j] < key) { u[j + 1] = u[j]; --j; }
            u[j + 1] = key;
        }
        float s = 0.f;
        for (int i = 0; i < 128; ++i) { s += u[i]; css[i] = s - KAPPA; }
        int rho = 0;
        for (int i = 0; i < 128; ++i)
            if (u[i] - css[i] / (float)(i + 1) > 0.f) rho++;
        if (rho < 1) rho = 1;
        float theta = css[rho - 1] / (float)rho;
        for (int j = 0; j < 128; ++j) {
            float w = W[r * 128 + j];
            float m = fmaxf(a[j] - theta, 0.f);
            float o = (w > 0.f) ? m : ((w < 0.f) ? -m : 0.f);
            WpT[j * 128 + r] = o;  // store transposed [k][c]
        }
    } else {
        for (int j = 0; j < 128; ++j) WpT[j * 128 + r] = W[r * 128 + j];
    }
}

// ---------- 2. transpose W_mlp [128,256] -> WT2 [256,128] ----------
__global__ void transpose_w_kernel(const float* __restrict__ Wm, float* __restrict__ WT2) {
    int idx = blockIdx.x * blockDim.x + threadIdx.x;  // over 128*256
    if (idx < 128 * 256) {
        int c = idx >> 8;     // 0..127
        int k = idx & 255;    // 0..255
        WT2[k * 128 + c] = Wm[idx];
    }
}

// ---------- 3. degree / CSR build ----------
__global__ void zero_kernel(int* __restrict__ counts, int* __restrict__ cursor, int n) {
    int i = blockIdx.x * blockDim.x + threadIdx.x;
    if (i < n) { counts[i] = 0; cursor[i] = 0; }
}

__global__ void count_kernel(const int* __restrict__ dst, int* __restrict__ counts, int e) {
    int i = blockIdx.x * blockDim.x + threadIdx.x;
    if (i < e) atomicAdd(&counts[dst[i]], 1);
}

__global__ void dinv_kernel(const int* __restrict__ counts, float* __restrict__ dinv, int n) {
    int i = blockIdx.x * blockDim.x + threadIdx.x;
    if (i < n) dinv[i] = rsqrtf((float)(counts[i] + 1));  // +1 = self loop
}

// exclusive prefix sum over counts -> offsets (single block, chunked Hillis-Steele)
__global__ __launch_bounds__(1024) void scan_kernel(const int* __restrict__ counts,
                                                    int* __restrict__ offsets, int n) {
    __shared__ int tmp[1024];
    __shared__ int carry;
    const int tid = threadIdx.x;
    if (tid == 0) carry = 0;
    __syncthreads();
    for (int base = 0; base < n; base += 1024) {
        int i = base + tid;
        int v = (i < n) ? counts[i] : 0;
        tmp[tid] = v;
        __syncthreads();
        int val = v;
        for (int off = 1; off < 1024; off <<= 1) {
            int add = (tid >= off) ? tmp[tid - off] : 0;
            __syncthreads();
            val += add;
            tmp[tid] = val;
            __syncthreads();
        }
        if (i < n) offsets[i] = carry + val - v;  // exclusive
        int total = tmp[1023];
        __syncthreads();
        if (tid == 0) carry += total;
        // barriers at top of next chunk order the carry update before its next read
    }
}

__global__ void fill_kernel(const int* __restrict__ src, const int* __restrict__ dst,
                            const int* __restrict__ offsets, int* __restrict__ cursor,
                            int* __restrict__ csr_src, int e) {
    int i = blockIdx.x * blockDim.x + threadIdx.x;
    if (i < e) {
        int d = dst[i];
        int p = atomicAdd(&cursor[d], 1);
        csr_src[offsets[d] + p] = src[i];
    }
}

// ---------- 4. GEMM: out = X[nrows,KD] @ WT[KD,128] ----------
// MODE 0: out_u32 = packed-bf16( dinv[row] * result )          (conv h')
// MODE 1: out_f   = relu( result + ADD )                       (mlp, ADD==out_f==d_out)
template <int KD, int MODE>
__global__ __launch_bounds__(256) void gemm_kernel(const float* __restrict__ X,
                                                   const float* __restrict__ WT,
                                                   const float* __restrict__ dinv,
                                                   const float* ADD,
                                                   unsigned int* __restrict__ out_u32,
                                                   float* out_f, int nrows) {
    __shared__ float  ldsX[32][132];       // [k][row], padded
    __shared__ float4 ldsW4[32 * 32];      // [k][col/4], 32x128 floats

    const int tid = threadIdx.x;
    const int rg = tid >> 4;   // 0..15 -> rows rg*8 .. rg*8+7
    const int cg = tid & 15;   // cols cg*4..+3 and 64+cg*4..+3
    const int row0 = blockIdx.x * 128;

    float acc[8][8];
#pragma unroll
    for (int i = 0; i < 8; ++i)
#pragma unroll
        for (int j = 0; j < 8; ++j) acc[i][j] = 0.f;

    const int rload = min(row0 + (tid >> 1), nrows - 1);  // 2 threads per row
    const int kk0 = (tid & 1) * 16;

    for (int k0 = 0; k0 < KD; k0 += 32) {
        __syncthreads();
        // stage X tile (128 rows x 32 k), transposed into LDS
        {
            const float4* xs =
                reinterpret_cast<const float4*>(&X[(size_t)rload * KD + k0 + kk0]);
            const int r = tid >> 1;
#pragma unroll
            for (int i = 0; i < 4; ++i) {
                float4 v = xs[i];
                int kk = kk0 + i * 4;
                ldsX[kk + 0][r] = v.x;
                ldsX[kk + 1][r] = v.y;
                ldsX[kk + 2][r] = v.z;
                ldsX[kk + 3][r] = v.w;
            }
        }
        // stage W tile (32 k x 128 cols), contiguous
        {
            const float4* wsrc = reinterpret_cast<const float4*>(&WT[(size_t)k0 * 128]);
#pragma unroll
            for (int i = 0; i < 4; ++i) ldsW4[i * 256 + tid] = wsrc[i * 256 + tid];
        }
        __syncthreads();

#pragma unroll 4
        for (int k = 0; k < 32; ++k) {
            const float4 e0 = *reinterpret_cast<const float4*>(&ldsX[k][rg * 8]);
            const float4 e1 = *reinterpret_cast<const float4*>(&ldsX[k][rg * 8 + 4]);
            const float4 w0 = ldsW4[k * 32 + cg];
            const float4 w1 = ldsW4[k * 32 + 16 + cg];
            const float ev[8] = {e0.x, e0.y, e0.z, e0.w, e1.x, e1.y, e1.z, e1.w};
            const float wv[8] = {w0.x, w0.y, w0.z, w0.w, w1.x, w1.y, w1.z, w1.w};
#pragma unroll
            for (int i = 0; i < 8; ++i)
#pragma unroll
                for (int j = 0; j < 8; ++j) acc[i][j] = fmaf(ev[i], wv[j], acc[i][j]);
        }
    }

#pragma unroll
    for (int i = 0; i < 8; ++i) {
        int r = row0 + rg * 8 + i;
        if (r >= nrows) break;
        if (MODE == 0) {
            float dv = dinv[r];
            unsigned int p01 = (unsigned int)f2bf(acc[i][0] * dv) |
                               ((unsigned int)f2bf(acc[i][1] * dv) << 16);
            unsigned int p23 = (unsigned int)f2bf(acc[i][2] * dv) |
                               ((unsigned int)f2bf(acc[i][3] * dv) << 16);
            unsigned int p45 = (unsigned int)f2bf(acc[i][4] * dv) |
                               ((unsigned int)f2bf(acc[i][5] * dv) << 16);
            unsigned int p67 = (unsigned int)f2bf(acc[i][6] * dv) |
                               ((unsigned int)f2bf(acc[i][7] * dv) << 16);
            uint2 q0 = {p01, p23};
            uint2 q1 = {p45, p67};
            *reinterpret_cast<uint2*>(&out_u32[(size_t)r * 64 + cg * 2]) = q0;
            *reinterpret_cast<uint2*>(&out_u32[(size_t)r * 64 + 32 + cg * 2]) = q1;
        } else {
            const float4 a0 = *reinterpret_cast<const float4*>(&ADD[(size_t)r * 128 + cg * 4]);
            const float4 a1 =
                *reinterpret_cast<const float4*>(&ADD[(size_t)r * 128 + 64 + cg * 4]);
            float4 o0, o1;
            o0.x = fmaxf(acc[i][0] + a0.x, 0.f);
            o0.y = fmaxf(acc[i][1] + a0.y, 0.f);
            o0.z = fmaxf(acc[i][2] + a0.z, 0.f);
            o0.w = fmaxf(acc[i][3] + a0.w, 0.f);
            o1.x = fmaxf(acc[i][4] + a1.x, 0.f);
            o1.y = fmaxf(acc[i][5] + a1.y, 0.f);
            o1.z = fmaxf(acc[i][6] + a1.z, 0.f);
            o1.w = fmaxf(acc[i][7] + a1.w, 0.f);
            *reinterpret_cast<float4*>(&out_f[(size_t)r * 128 + cg * 4]) = o0;
            *reinterpret_cast<float4*>(&out_f[(size_t)r * 128 + 64 + cg * 4]) = o1;
        }
    }
}

// ---------- 5. aggregation: agg[v] = dinv[v] * (sum_{u->v} h'[u] + h'[v]) ----------
// h' is packed bf16 [N][64] uints (128 features). One wave per node, 4 nodes/block.
__global__ __launch_bounds__(256) void agg_kernel(const unsigned int* __restrict__ h,
                                                  const int* __restrict__ csr_src,
                                                  const int* __restrict__ offsets,
                                                  const int* __restrict__ counts,
                                                  const float* __restrict__ dinv,
                                                  float* __restrict__ agg, int n) {
    int v = blockIdx.x * 4 + (threadIdx.x >> 6);
    if (v >= n) return;
    int t = threadIdx.x & 63;  // features 2t, 2t+1
    int start = offsets[v];
    int cnt = counts[v];
    float a0 = 0.f, a1 = 0.f;
    for (int i = 0; i < cnt; ++i) {
        int s = csr_src[start + i];
        unsigned int val = h[(size_t)s * 64 + t];
        a0 += __uint_as_float(val << 16);
        a1 += __uint_as_float(val & 0xffff0000u);
    }
    {  // self loop
        unsigned int val = h[(size_t)v * 64 + t];
        a0 += __uint_as_float(val << 16);
        a1 += __uint_as_float(val & 0xffff0000u);
    }
    float dv = dinv[v];
    float2 o = {dv * a0, dv * a1};
    *reinterpret_cast<float2*>(&agg[(size_t)v * 128 + 2 * t]) = o;
}

// ---------- launch ----------
extern "C" void kernel_launch(void* const* d_in, const int* in_sizes, int n_in,
                              void* d_out, int out_size, void* d_ws, size_t ws_size,
                              hipStream_t stream) {
    const float* features = (const float*)d_in[0];  // [N,256]
    const int*   edge     = (const int*)d_in[1];    // [2,E]
    const float* emb      = (const float*)d_in[2];  // [N,128]
    const float* Wconv    = (const float*)d_in[3];  // [128,128]
    const float* Wmlp     = (const float*)d_in[4];  // [128,256]
    float* out = (float*)d_out;                     // [N,128]

    const int N = in_sizes[0] / 256;
    const int E = in_sizes[1] / 2;
    const int* src = edge;
    const int* dst = edge + E;

    char* ws = (char*)d_ws;
    size_t o = 0;
    auto take = [&](size_t b) {
        size_t cur = o;
        o += (b + 255) & ~(size_t)255;
        return cur;
    };
    float*        WpT     = (float*)(ws + take((size_t)128 * 128 * 4));
    float*        WT2     = (float*)(ws + take((size_t)256 * 128 * 4));
    int*          counts  = (int*)(ws + take((size_t)N * 4));
    int*          cursor  = (int*)(ws + take((size_t)N * 4));
    float*        dinv    = (float*)(ws + take((size_t)N * 4));
    int*          offsets = (int*)(ws + take((size_t)(N + 1) * 4));
    int*          csr_src = (int*)(ws + take((size_t)E * 4));
    unsigned int* hbuf    = (unsigned int*)(ws + take((size_t)N * 64 * 4));
    (void)ws_size; (void)n_in; (void)out_size;

    hipLaunchKernelGGL(proj_kernel, dim3(1), dim3(128), 0, stream, Wconv, WpT);
    hipLaunchKernelGGL(transpose_w_kernel, dim3((128 * 256 + 255) / 256), dim3(256), 0, stream,
                       Wmlp, WT2);
    hipLaunchKernelGGL(zero_kernel, dim3((N + 255) / 256), dim3(256), 0, stream, counts, cursor, N);
    hipLaunchKernelGGL(count_kernel, dim3((E + 255) / 256), dim3(256), 0, stream, dst, counts, E);
    hipLaunchKernelGGL(dinv_kernel, dim3((N + 255) / 256), dim3(256), 0, stream, counts, dinv, N);
    hipLaunchKernelGGL(scan_kernel, dim3(1), dim3(1024), 0, stream, counts, offsets, N);
    hipLaunchKernelGGL(fill_kernel, dim3((E + 255) / 256), dim3(256), 0, stream, src, dst, offsets,
                       cursor, csr_src, E);
    // h' = bf16( dinv[row] * (emb @ WpT) )
    hipLaunchKernelGGL((gemm_kernel<128, 0>), dim3((N + 127) / 128), dim3(256), 0, stream, emb,
                       WpT, dinv, (const float*)nullptr, hbuf, (float*)nullptr, N);
    // agg -> d_out (staging)
    hipLaunchKernelGGL(agg_kernel, dim3((N + 3) / 4), dim3(256), 0, stream, hbuf, csr_src, offsets,
                       counts, dinv, out, N);
    // out = relu(features @ WT2 + agg)
    hipLaunchKernelGGL((gemm_kernel<256, 1>), dim3((N + 127) / 128), dim3(256), 0, stream, features,
                       WT2, (const float*)nullptr, out, (unsigned int*)nullptr, out, N);
}

// Round 2
// 877.685 us; speedup vs baseline: 2.4083x; 2.4083x over previous
//
#include <hip/hip_runtime.h>

#define KAPPA 0.95f

// ---------- bf16 helpers (manual, round-to-nearest-even) ----------
static __device__ inline unsigned short f2bf(float f) {
    unsigned int u = __float_as_uint(f);
    unsigned int rounding = 0x7fffu + ((u >> 16) & 1u);
    u += rounding;
    return (unsigned short)(u >> 16);
}

// ---------- 1. proj_norm_inf on W_conv: one BLOCK per row, bitonic in LDS ----------
__global__ __launch_bounds__(128) void proj_kernel(const float* __restrict__ W,
                                                   float* __restrict__ WpT) {
    const int r = blockIdx.x;    // row 0..127
    const int tid = threadIdx.x; // col 0..127
    __shared__ float s[128];     // sorted |w| (ascending)
    __shared__ float c[128];     // inclusive cumsum of descending u
    __shared__ int rho_s;

    const float w = W[r * 128 + tid];
    const float a = fabsf(w);
    s[tid] = a;
    if (tid == 0) rho_s = 0;
    __syncthreads();

    // bitonic sort ascending
    for (int k = 2; k <= 128; k <<= 1) {
        for (int j = k >> 1; j > 0; j >>= 1) {
            int ixj = tid ^ j;
            if (ixj > tid) {
                bool up = ((tid & k) == 0);
                float x = s[tid], y = s[ixj];
                if ((x > y) == up) { s[tid] = y; s[ixj] = x; }
            }
            __syncthreads();
        }
    }

    // u = descending view; inclusive scan of u
    const float u = s[127 - tid];
    c[tid] = u;
    __syncthreads();
    for (int off = 1; off < 128; off <<= 1) {
        float add = (tid >= off) ? c[tid - off] : 0.f;
        __syncthreads();
        c[tid] += add;
        __syncthreads();
    }
    const float rowsum = c[127];
    const float css = c[tid] - KAPPA;
    if (u - css / (float)(tid + 1) > 0.f) atomicAdd(&rho_s, 1);
    __syncthreads();

    float out = w;
    if (rowsum > KAPPA) {
        int rho = max(rho_s, 1);
        float theta = (c[rho - 1] - KAPPA) / (float)rho;
        float m = fmaxf(a - theta, 0.f);
        out = (w > 0.f) ? m : ((w < 0.f) ? -m : 0.f);
    }
    WpT[tid * 128 + r] = out;  // store transposed [k][c]
}

// ---------- 2. transpose W_mlp [128,256] -> WT2 [256,128] ----------
__global__ void transpose_w_kernel(const float* __restrict__ Wm, float* __restrict__ WT2) {
    int idx = blockIdx.x * blockDim.x + threadIdx.x;  // over 128*256
    if (idx < 128 * 256) {
        int c = idx >> 8;     // 0..127
        int k = idx & 255;    // 0..255
        WT2[k * 128 + c] = Wm[idx];
    }
}

// ---------- 3. degree / CSR build ----------
__global__ void zero_kernel(int* __restrict__ counts, int* __restrict__ cursor, int n) {
    int i = blockIdx.x * blockDim.x + threadIdx.x;
    if (i < n) { counts[i] = 0; cursor[i] = 0; }
}

__global__ void count_kernel(const int* __restrict__ dst, int* __restrict__ counts, int e) {
    int i = blockIdx.x * blockDim.x + threadIdx.x;
    if (i < e) atomicAdd(&counts[dst[i]], 1);
}

__global__ void dinv_kernel(const int* __restrict__ counts, float* __restrict__ dinv, int n) {
    int i = blockIdx.x * blockDim.x + threadIdx.x;
    if (i < n) dinv[i] = rsqrtf((float)(counts[i] + 1));  // +1 = self loop
}

// exclusive prefix sum over counts -> offsets (single block, chunked Hillis-Steele)
__global__ __launch_bounds__(1024) void scan_kernel(const int* __restrict__ counts,
                                                    int* __restrict__ offsets, int n) {
    __shared__ int tmp[1024];
    __shared__ int carry;
    const int tid = threadIdx.x;
    if (tid == 0) carry = 0;
    __syncthreads();
    for (int base = 0; base < n; base += 1024) {
        int i = base + tid;
        int v = (i < n) ? counts[i] : 0;
        tmp[tid] = v;
        __syncthreads();
        int val = v;
        for (int off = 1; off < 1024; off <<= 1) {
            int add = (tid >= off) ? tmp[tid - off] : 0;
            __syncthreads();
            val += add;
            tmp[tid] = val;
            __syncthreads();
        }
        if (i < n) offsets[i] = carry + val - v;  // exclusive
        int total = tmp[1023];
        __syncthreads();
        if (tid == 0) carry += total;
        // barriers at top of next chunk order the carry update before its next read
    }
}

__global__ void fill_kernel(const int* __restrict__ src, const int* __restrict__ dst,
                            const int* __restrict__ offsets, int* __restrict__ cursor,
                            int* __restrict__ csr_src, int e) {
    int i = blockIdx.x * blockDim.x + threadIdx.x;
    if (i < e) {
        int d = dst[i];
        int p = atomicAdd(&cursor[d], 1);
        csr_src[offsets[d] + p] = src[i];
    }
}

// ---------- 4. GEMM: out = X[nrows,KD] @ WT[KD,128] ----------
// MODE 0: out_u32 = packed-bf16( dinv[row] * result )          (conv h')
// MODE 1: out_f   = relu( result + ADD )                       (mlp, ADD==out_f==d_out)
template <int KD, int MODE>
__global__ __launch_bounds__(256) void gemm_kernel(const float* __restrict__ X,
                                                   const float* __restrict__ WT,
                                                   const float* __restrict__ dinv,
                                                   const float* ADD,
                                                   unsigned int* __restrict__ out_u32,
                                                   float* out_f, int nrows) {
    __shared__ float  ldsX[32][132];       // [k][row], padded
    __shared__ float4 ldsW4[32 * 32];      // [k][col/4], 32x128 floats

    const int tid = threadIdx.x;
    const int rg = tid >> 4;   // 0..15 -> rows rg*8 .. rg*8+7
    const int cg = tid & 15;   // cols cg*4..+3 and 64+cg*4..+3
    const int row0 = blockIdx.x * 128;

    float acc[8][8];
#pragma unroll
    for (int i = 0; i < 8; ++i)
#pragma unroll
        for (int j = 0; j < 8; ++j) acc[i][j] = 0.f;

    const int rload = min(row0 + (tid >> 1), nrows - 1);  // 2 threads per row
    const int kk0 = (tid & 1) * 16;

    for (int k0 = 0; k0 < KD; k0 += 32) {
        __syncthreads();
        // stage X tile (128 rows x 32 k), transposed into LDS
        {
            const float4* xs =
                reinterpret_cast<const float4*>(&X[(size_t)rload * KD + k0 + kk0]);
            const int r = tid >> 1;
#pragma unroll
            for (int i = 0; i < 4; ++i) {
                float4 v = xs[i];
                int kk = kk0 + i * 4;
                ldsX[kk + 0][r] = v.x;
                ldsX[kk + 1][r] = v.y;
                ldsX[kk + 2][r] = v.z;
                ldsX[kk + 3][r] = v.w;
            }
        }
        // stage W tile (32 k x 128 cols), contiguous
        {
            const float4* wsrc = reinterpret_cast<const float4*>(&WT[(size_t)k0 * 128]);
#pragma unroll
            for (int i = 0; i < 4; ++i) ldsW4[i * 256 + tid] = wsrc[i * 256 + tid];
        }
        __syncthreads();

#pragma unroll 4
        for (int k = 0; k < 32; ++k) {
            const float4 e0 = *reinterpret_cast<const float4*>(&ldsX[k][rg * 8]);
            const float4 e1 = *reinterpret_cast<const float4*>(&ldsX[k][rg * 8 + 4]);
            const float4 w0 = ldsW4[k * 32 + cg];
            const float4 w1 = ldsW4[k * 32 + 16 + cg];
            const float ev[8] = {e0.x, e0.y, e0.z, e0.w, e1.x, e1.y, e1.z, e1.w};
            const float wv[8] = {w0.x, w0.y, w0.z, w0.w, w1.x, w1.y, w1.z, w1.w};
#pragma unroll
            for (int i = 0; i < 8; ++i)
#pragma unroll
                for (int j = 0; j < 8; ++j) acc[i][j] = fmaf(ev[i], wv[j], acc[i][j]);
        }
    }

#pragma unroll
    for (int i = 0; i < 8; ++i) {
        int r = row0 + rg * 8 + i;
        if (r >= nrows) break;
        if (MODE == 0) {
            float dv = dinv[r];
            unsigned int p01 = (unsigned int)f2bf(acc[i][0] * dv) |
                               ((unsigned int)f2bf(acc[i][1] * dv) << 16);
            unsigned int p23 = (unsigned int)f2bf(acc[i][2] * dv) |
                               ((unsigned int)f2bf(acc[i][3] * dv) << 16);
            unsigned int p45 = (unsigned int)f2bf(acc[i][4] * dv) |
                               ((unsigned int)f2bf(acc[i][5] * dv) << 16);
            unsigned int p67 = (unsigned int)f2bf(acc[i][6] * dv) |
                               ((unsigned int)f2bf(acc[i][7] * dv) << 16);
            uint2 q0 = {p01, p23};
            uint2 q1 = {p45, p67};
            *reinterpret_cast<uint2*>(&out_u32[(size_t)r * 64 + cg * 2]) = q0;
            *reinterpret_cast<uint2*>(&out_u32[(size_t)r * 64 + 32 + cg * 2]) = q1;
        } else {
            const float4 a0 = *reinterpret_cast<const float4*>(&ADD[(size_t)r * 128 + cg * 4]);
            const float4 a1 =
                *reinterpret_cast<const float4*>(&ADD[(size_t)r * 128 + 64 + cg * 4]);
            float4 o0, o1;
            o0.x = fmaxf(acc[i][0] + a0.x, 0.f);
            o0.y = fmaxf(acc[i][1] + a0.y, 0.f);
            o0.z = fmaxf(acc[i][2] + a0.z, 0.f);
            o0.w = fmaxf(acc[i][3] + a0.w, 0.f);
            o1.x = fmaxf(acc[i][4] + a1.x, 0.f);
            o1.y = fmaxf(acc[i][5] + a1.y, 0.f);
            o1.z = fmaxf(acc[i][6] + a1.z, 0.f);
            o1.w = fmaxf(acc[i][7] + a1.w, 0.f);
            *reinterpret_cast<float4*>(&out_f[(size_t)r * 128 + cg * 4]) = o0;
            *reinterpret_cast<float4*>(&out_f[(size_t)r * 128 + 64 + cg * 4]) = o1;
        }
    }
}

// ---------- 5. aggregation: agg[v] = dinv[v] * (sum_{u->v} h'[u] + h'[v]) ----------
// h' is packed bf16 [N][64] uints (128 features). One wave per node, 4 nodes/block.
__global__ __launch_bounds__(256) void agg_kernel(const unsigned int* __restrict__ h,
                                                  const int* __restrict__ csr_src,
                                                  const int* __restrict__ offsets,
                                                  const int* __restrict__ counts,
                                                  const float* __restrict__ dinv,
                                                  float* __restrict__ agg, int n) {
    int v = blockIdx.x * 4 + (threadIdx.x >> 6);
    if (v >= n) return;
    int t = threadIdx.x & 63;  // features 2t, 2t+1
    int start = offsets[v];
    int cnt = counts[v];
    float a0 = 0.f, a1 = 0.f;
    for (int i = 0; i < cnt; ++i) {
        int s = csr_src[start + i];
        unsigned int val = h[(size_t)s * 64 + t];
        a0 += __uint_as_float(val << 16);
        a1 += __uint_as_float(val & 0xffff0000u);
    }
    {  // self loop
        unsigned int val = h[(size_t)v * 64 + t];
        a0 += __uint_as_float(val << 16);
        a1 += __uint_as_float(val & 0xffff0000u);
    }
    float dv = dinv[v];
    float2 o = {dv * a0, dv * a1};
    *reinterpret_cast<float2*>(&agg[(size_t)v * 128 + 2 * t]) = o;
}

// ---------- launch ----------
extern "C" void kernel_launch(void* const* d_in, const int* in_sizes, int n_in,
                              void* d_out, int out_size, void* d_ws, size_t ws_size,
                              hipStream_t stream) {
    const float* features = (const float*)d_in[0];  // [N,256]
    const int*   edge     = (const int*)d_in[1];    // [2,E]
    const float* emb      = (const float*)d_in[2];  // [N,128]
    const float* Wconv    = (const float*)d_in[3];  // [128,128]
    const float* Wmlp     = (const float*)d_in[4];  // [128,256]
    float* out = (float*)d_out;                     // [N,128]

    const int N = in_sizes[0] / 256;
    const int E = in_sizes[1] / 2;
    const int* src = edge;
    const int* dst = edge + E;

    char* ws = (char*)d_ws;
    size_t o = 0;
    auto take = [&](size_t b) {
        size_t cur = o;
        o += (b + 255) & ~(size_t)255;
        return cur;
    };
    float*        WpT     = (float*)(ws + take((size_t)128 * 128 * 4));
    float*        WT2     = (float*)(ws + take((size_t)256 * 128 * 4));
    int*          counts  = (int*)(ws + take((size_t)N * 4));
    int*          cursor  = (int*)(ws + take((size_t)N * 4));
    float*        dinv    = (float*)(ws + take((size_t)N * 4));
    int*          offsets = (int*)(ws + take((size_t)(N + 1) * 4));
    int*          csr_src = (int*)(ws + take((size_t)E * 4));
    unsigned int* hbuf    = (unsigned int*)(ws + take((size_t)N * 64 * 4));
    (void)ws_size; (void)n_in; (void)out_size;

    hipLaunchKernelGGL(proj_kernel, dim3(128), dim3(128), 0, stream, Wconv, WpT);
    hipLaunchKernelGGL(transpose_w_kernel, dim3((128 * 256 + 255) / 256), dim3(256), 0, stream,
                       Wmlp, WT2);
    hipLaunchKernelGGL(zero_kernel, dim3((N + 255) / 256), dim3(256), 0, stream, counts, cursor, N);
    hipLaunchKernelGGL(count_kernel, dim3((E + 255) / 256), dim3(256), 0, stream, dst, counts, E);
    hipLaunchKernelGGL(dinv_kernel, dim3((N + 255) / 256), dim3(256), 0, stream, counts, dinv, N);
    hipLaunchKernelGGL(scan_kernel, dim3(1), dim3(1024), 0, stream, counts, offsets, N);
    hipLaunchKernelGGL(fill_kernel, dim3((E + 255) / 256), dim3(256), 0, stream, src, dst, offsets,
                       cursor, csr_src, E);
    // h' = bf16( dinv[row] * (emb @ WpT) )
    hipLaunchKernelGGL((gemm_kernel<128, 0>), dim3((N + 127) / 128), dim3(256), 0, stream, emb,
                       WpT, dinv, (const float*)nullptr, hbuf, (float*)nullptr, N);
    // agg -> d_out (staging)
    hipLaunchKernelGGL(agg_kernel, dim3((N + 3) / 4), dim3(256), 0, stream, hbuf, csr_src, offsets,
                       counts, dinv, out, N);
    // out = relu(features @ WT2 + agg)
    hipLaunchKernelGGL((gemm_kernel<256, 1>), dim3((N + 127) / 128), dim3(256), 0, stream, features,
                       WT2, (const float*)nullptr, out, (unsigned int*)nullptr, out, N);
}

// Round 3
// 668.571 us; speedup vs baseline: 3.1616x; 1.3128x over previous
//
#include <hip/hip_runtime.h>

#define KAPPA 0.95f

// ---------- bf16 helpers ----------
static __device__ inline unsigned short f2bf(float f) {
    unsigned int u = __float_as_uint(f);
    unsigned int rounding = 0x7fffu + ((u >> 16) & 1u);
    u += rounding;
    return (unsigned short)(u >> 16);
}
static __device__ inline float bflo(unsigned int u) { return __uint_as_float(u << 16); }
static __device__ inline float bfhi(unsigned int u) { return __uint_as_float(u & 0xffff0000u); }

// ---------- 1. proj_norm_inf on W_conv: one BLOCK per row, bitonic in LDS ----------
__global__ __launch_bounds__(128) void proj_kernel(const float* __restrict__ W,
                                                   float* __restrict__ WpT) {
    const int r = blockIdx.x;    // row 0..127
    const int tid = threadIdx.x; // col 0..127
    __shared__ float s[128];
    __shared__ float c[128];
    __shared__ int rho_s;

    const float w = W[r * 128 + tid];
    const float a = fabsf(w);
    s[tid] = a;
    if (tid == 0) rho_s = 0;
    __syncthreads();

    // bitonic sort ascending
    for (int k = 2; k <= 128; k <<= 1) {
        for (int j = k >> 1; j > 0; j >>= 1) {
            int ixj = tid ^ j;
            if (ixj > tid) {
                bool up = ((tid & k) == 0);
                float x = s[tid], y = s[ixj];
                if ((x > y) == up) { s[tid] = y; s[ixj] = x; }
            }
            __syncthreads();
        }
    }

    const float u = s[127 - tid];  // descending view
    c[tid] = u;
    __syncthreads();
    for (int off = 1; off < 128; off <<= 1) {
        float add = (tid >= off) ? c[tid - off] : 0.f;
        __syncthreads();
        c[tid] += add;
        __syncthreads();
    }
    const float rowsum = c[127];
    const float css = c[tid] - KAPPA;
    if (u - css / (float)(tid + 1) > 0.f) atomicAdd(&rho_s, 1);
    __syncthreads();

    float out = w;
    if (rowsum > KAPPA) {
        int rho = max(rho_s, 1);
        float theta = (c[rho - 1] - KAPPA) / (float)rho;
        float m = fmaxf(a - theta, 0.f);
        out = (w > 0.f) ? m : ((w < 0.f) ? -m : 0.f);
    }
    WpT[tid * 128 + r] = out;  // transposed [k][c]
}

// ---------- 2. transpose W_mlp [128,256] -> WT2 [256,128] ----------
__global__ void transpose_w_kernel(const float* __restrict__ Wm, float* __restrict__ WT2) {
    int idx = blockIdx.x * blockDim.x + threadIdx.x;
    if (idx < 128 * 256) {
        int c = idx >> 8;
        int k = idx & 255;
        WT2[k * 128 + c] = Wm[idx];
    }
}

// ---------- 3. degree / CSR build ----------
__global__ void zero_kernel(int* __restrict__ counts, int n) {
    int i = blockIdx.x * blockDim.x + threadIdx.x;
    if (i < n) counts[i] = 0;
}

__global__ void count_kernel(const int* __restrict__ dst, int* __restrict__ counts, int e) {
    int i = blockIdx.x * blockDim.x + threadIdx.x;
    if (i < e) atomicAdd(&counts[dst[i]], 1);
}

// multi-block exclusive scan of counts -> cursor; also dinv. 1024 threads/block.
__global__ __launch_bounds__(1024) void scan1_kernel(const int* __restrict__ counts,
                                                     int* __restrict__ partials, int n) {
    __shared__ int tmp[1024];
    int i = blockIdx.x * 1024 + threadIdx.x;
    tmp[threadIdx.x] = (i < n) ? counts[i] : 0;
    __syncthreads();
    for (int off = 512; off > 0; off >>= 1) {
        if (threadIdx.x < off) tmp[threadIdx.x] += tmp[threadIdx.x + off];
        __syncthreads();
    }
    if (threadIdx.x == 0) partials[blockIdx.x] = tmp[0];
}

__global__ __launch_bounds__(1024) void scan2_kernel(int* __restrict__ partials, int nb) {
    __shared__ int tmp[1024];
    const int tid = threadIdx.x;
    int v = (tid < nb) ? partials[tid] : 0;
    tmp[tid] = v;
    __syncthreads();
    int val = v;
    for (int off = 1; off < 1024; off <<= 1) {
        int add = (tid >= off) ? tmp[tid - off] : 0;
        __syncthreads();
        val += add;
        tmp[tid] = val;
        __syncthreads();
    }
    if (tid < nb) partials[tid] = val - v;  // exclusive
}

__global__ __launch_bounds__(1024) void scan3_kernel(const int* __restrict__ counts,
                                                     const int* __restrict__ partials,
                                                     int* __restrict__ cursor,
                                                     float* __restrict__ dinv, int n) {
    __shared__ int tmp[1024];
    const int tid = threadIdx.x;
    int i = blockIdx.x * 1024 + tid;
    int v = (i < n) ? counts[i] : 0;
    tmp[tid] = v;
    __syncthreads();
    int val = v;
    for (int off = 1; off < 1024; off <<= 1) {
        int add = (tid >= off) ? tmp[tid - off] : 0;
        __syncthreads();
        val += add;
        tmp[tid] = val;
        __syncthreads();
    }
    if (i < n) {
        cursor[i] = partials[blockIdx.x] + val - v;  // exclusive offset
        dinv[i] = rsqrtf((float)(v + 1));            // +1 self loop
    }
}

__global__ void fill_kernel(const int* __restrict__ src, const int* __restrict__ dst,
                            int* __restrict__ cursor, int* __restrict__ csr_src, int e) {
    int i = blockIdx.x * blockDim.x + threadIdx.x;
    if (i < e) {
        int p = atomicAdd(&cursor[dst[i]], 1);
        csr_src[p] = src[i];
    }
}

// ---------- 4. GEMM: out = X[nrows,KD] @ WT[KD,128] ----------
template <int KD, int MODE>
__global__ __launch_bounds__(256) void gemm_kernel(const float* __restrict__ X,
                                                   const float* __restrict__ WT,
                                                   const float* __restrict__ dinv,
                                                   const float* ADD,
                                                   unsigned int* __restrict__ out_u32,
                                                   float* out_f, int nrows) {
    __shared__ float  ldsX[32][132];
    __shared__ float4 ldsW4[32 * 32];

    const int tid = threadIdx.x;
    const int rg = tid >> 4;
    const int cg = tid & 15;
    const int row0 = blockIdx.x * 128;

    float acc[8][8];
#pragma unroll
    for (int i = 0; i < 8; ++i)
#pragma unroll
        for (int j = 0; j < 8; ++j) acc[i][j] = 0.f;

    const int rload = min(row0 + (tid >> 1), nrows - 1);
    const int kk0 = (tid & 1) * 16;

    for (int k0 = 0; k0 < KD; k0 += 32) {
        __syncthreads();
        {
            const float4* xs =
                reinterpret_cast<const float4*>(&X[(size_t)rload * KD + k0 + kk0]);
            const int r = tid >> 1;
#pragma unroll
            for (int i = 0; i < 4; ++i) {
                float4 v = xs[i];
                int kk = kk0 + i * 4;
                ldsX[kk + 0][r] = v.x;
                ldsX[kk + 1][r] = v.y;
                ldsX[kk + 2][r] = v.z;
                ldsX[kk + 3][r] = v.w;
            }
        }
        {
            const float4* wsrc = reinterpret_cast<const float4*>(&WT[(size_t)k0 * 128]);
#pragma unroll
            for (int i = 0; i < 4; ++i) ldsW4[i * 256 + tid] = wsrc[i * 256 + tid];
        }
        __syncthreads();

#pragma unroll 4
        for (int k = 0; k < 32; ++k) {
            const float4 e0 = *reinterpret_cast<const float4*>(&ldsX[k][rg * 8]);
            const float4 e1 = *reinterpret_cast<const float4*>(&ldsX[k][rg * 8 + 4]);
            const float4 w0 = ldsW4[k * 32 + cg];
            const float4 w1 = ldsW4[k * 32 + 16 + cg];
            const float ev[8] = {e0.x, e0.y, e0.z, e0.w, e1.x, e1.y, e1.z, e1.w};
            const float wv[8] = {w0.x, w0.y, w0.z, w0.w, w1.x, w1.y, w1.z, w1.w};
#pragma unroll
            for (int i = 0; i < 8; ++i)
#pragma unroll
                for (int j = 0; j < 8; ++j) acc[i][j] = fmaf(ev[i], wv[j], acc[i][j]);
        }
    }

#pragma unroll
    for (int i = 0; i < 8; ++i) {
        int r = row0 + rg * 8 + i;
        if (r >= nrows) break;
        if (MODE == 0) {
            float dv = dinv[r];
            unsigned int p01 = (unsigned int)f2bf(acc[i][0] * dv) |
                               ((unsigned int)f2bf(acc[i][1] * dv) << 16);
            unsigned int p23 = (unsigned int)f2bf(acc[i][2] * dv) |
                               ((unsigned int)f2bf(acc[i][3] * dv) << 16);
            unsigned int p45 = (unsigned int)f2bf(acc[i][4] * dv) |
                               ((unsigned int)f2bf(acc[i][5] * dv) << 16);
            unsigned int p67 = (unsigned int)f2bf(acc[i][6] * dv) |
                               ((unsigned int)f2bf(acc[i][7] * dv) << 16);
            uint2 q0 = {p01, p23};
            uint2 q1 = {p45, p67};
            *reinterpret_cast<uint2*>(&out_u32[(size_t)r * 64 + cg * 2]) = q0;
            *reinterpret_cast<uint2*>(&out_u32[(size_t)r * 64 + 32 + cg * 2]) = q1;
        } else {
            const float4 a0 = *reinterpret_cast<const float4*>(&ADD[(size_t)r * 128 + cg * 4]);
            const float4 a1 =
                *reinterpret_cast<const float4*>(&ADD[(size_t)r * 128 + 64 + cg * 4]);
            float4 o0, o1;
            o0.x = fmaxf(acc[i][0] + a0.x, 0.f);
            o0.y = fmaxf(acc[i][1] + a0.y, 0.f);
            o0.z = fmaxf(acc[i][2] + a0.z, 0.f);
            o0.w = fmaxf(acc[i][3] + a0.w, 0.f);
            o1.x = fmaxf(acc[i][4] + a1.x, 0.f);
            o1.y = fmaxf(acc[i][5] + a1.y, 0.f);
            o1.z = fmaxf(acc[i][6] + a1.z, 0.f);
            o1.w = fmaxf(acc[i][7] + a1.w, 0.f);
            *reinterpret_cast<float4*>(&out_f[(size_t)r * 128 + cg * 4]) = o0;
            *reinterpret_cast<float4*>(&out_f[(size_t)r * 128 + 64 + cg * 4]) = o1;
        }
    }
}

// ---------- 5. aggregation: agg[v] = dinv[v] * (sum_{u->v} h'[u] + h'[v]) ----------
// h' packed bf16 [N][64] uints. One wave per node; wave = 4 groups x 16 lanes;
// each group processes a different edge concurrently (4 rows in flight),
// each lane loads uint4 (16B = 8 features). Cross-group shfl_xor reduce.
__global__ __launch_bounds__(256) void agg_kernel(const unsigned int* __restrict__ h,
                                                  const int* __restrict__ csr_src,
                                                  const int* __restrict__ cursor,
                                                  const int* __restrict__ counts,
                                                  const float* __restrict__ dinv,
                                                  float* __restrict__ agg, int n) {
    int v = blockIdx.x * 4 + (threadIdx.x >> 6);
    if (v >= n) return;
    const int lane = threadIdx.x & 63;
    const int eg = lane >> 4;  // edge slot 0..3
    const int c = lane & 15;   // uint4 chunk -> features c*8..c*8+7
    const int cnt = counts[v];
    const int start = cursor[v] - cnt;  // cursor was advanced by fill to end

    const uint4* hp = reinterpret_cast<const uint4*>(h);
    float acc[8];
#pragma unroll
    for (int j = 0; j < 8; ++j) acc[j] = 0.f;

    int s_next = (eg < cnt) ? csr_src[start + eg] : -1;
    for (int base = 0; base < cnt; base += 4) {
        int s = s_next;
        int nx = base + 4 + eg;
        s_next = (nx < cnt) ? csr_src[start + nx] : -1;
        if (s >= 0) {
            uint4 val = hp[(size_t)s * 16 + c];
            acc[0] += bflo(val.x); acc[1] += bfhi(val.x);
            acc[2] += bflo(val.y); acc[3] += bfhi(val.y);
            acc[4] += bflo(val.z); acc[5] += bfhi(val.z);
            acc[6] += bflo(val.w); acc[7] += bfhi(val.w);
        }
    }
    if (eg == 0) {  // self loop
        uint4 val = hp[(size_t)v * 16 + c];
        acc[0] += bflo(val.x); acc[1] += bfhi(val.x);
        acc[2] += bflo(val.y); acc[3] += bfhi(val.y);
        acc[4] += bflo(val.z); acc[5] += bfhi(val.z);
        acc[6] += bflo(val.w); acc[7] += bfhi(val.w);
    }
#pragma unroll
    for (int j = 0; j < 8; ++j) {
        acc[j] += __shfl_xor(acc[j], 16);
        acc[j] += __shfl_xor(acc[j], 32);
    }
    if (eg == 0) {
        float dv = dinv[v];
        float4 o0 = {acc[0] * dv, acc[1] * dv, acc[2] * dv, acc[3] * dv};
        float4 o1 = {acc[4] * dv, acc[5] * dv, acc[6] * dv, acc[7] * dv};
        *reinterpret_cast<float4*>(&agg[(size_t)v * 128 + c * 8]) = o0;
        *reinterpret_cast<float4*>(&agg[(size_t)v * 128 + c * 8 + 4]) = o1;
    }
}

// ---------- launch ----------
extern "C" void kernel_launch(void* const* d_in, const int* in_sizes, int n_in,
                              void* d_out, int out_size, void* d_ws, size_t ws_size,
                              hipStream_t stream) {
    const float* features = (const float*)d_in[0];  // [N,256]
    const int*   edge     = (const int*)d_in[1];    // [2,E]
    const float* emb      = (const float*)d_in[2];  // [N,128]
    const float* Wconv    = (const float*)d_in[3];  // [128,128]
    const float* Wmlp     = (const float*)d_in[4];  // [128,256]
    float* out = (float*)d_out;                     // [N,128]

    const int N = in_sizes[0] / 256;
    const int E = in_sizes[1] / 2;
    const int* src = edge;
    const int* dst = edge + E;
    const int NB = (N + 1023) / 1024;

    char* ws = (char*)d_ws;
    size_t o = 0;
    auto take = [&](size_t b) {
        size_t cur = o;
        o += (b + 255) & ~(size_t)255;
        return cur;
    };
    float*        WpT      = (float*)(ws + take((size_t)128 * 128 * 4));
    float*        WT2      = (float*)(ws + take((size_t)256 * 128 * 4));
    int*          counts   = (int*)(ws + take((size_t)N * 4));
    int*          cursor   = (int*)(ws + take((size_t)N * 4));
    float*        dinv     = (float*)(ws + take((size_t)N * 4));
    int*          partials = (int*)(ws + take((size_t)(NB + 1) * 4));
    int*          csr_src  = (int*)(ws + take((size_t)E * 4));
    unsigned int* hbuf     = (unsigned int*)(ws + take((size_t)N * 64 * 4));
    (void)ws_size; (void)n_in; (void)out_size;

    hipLaunchKernelGGL(proj_kernel, dim3(128), dim3(128), 0, stream, Wconv, WpT);
    hipLaunchKernelGGL(transpose_w_kernel, dim3((128 * 256 + 255) / 256), dim3(256), 0, stream,
                       Wmlp, WT2);
    hipLaunchKernelGGL(zero_kernel, dim3((N + 255) / 256), dim3(256), 0, stream, counts, N);
    hipLaunchKernelGGL(count_kernel, dim3((E + 255) / 256), dim3(256), 0, stream, dst, counts, E);
    hipLaunchKernelGGL(scan1_kernel, dim3(NB), dim3(1024), 0, stream, counts, partials, N);
    hipLaunchKernelGGL(scan2_kernel, dim3(1), dim3(1024), 0, stream, partials, NB);
    hipLaunchKernelGGL(scan3_kernel, dim3(NB), dim3(1024), 0, stream, counts, partials, cursor,
                       dinv, N);
    // h' = bf16( dinv[row] * (emb @ WpT) )   (needs dinv from scan3)
    hipLaunchKernelGGL((gemm_kernel<128, 0>), dim3((N + 127) / 128), dim3(256), 0, stream, emb,
                       WpT, dinv, (const float*)nullptr, hbuf, (float*)nullptr, N);
    hipLaunchKernelGGL(fill_kernel, dim3((E + 255) / 256), dim3(256), 0, stream, src, dst, cursor,
                       csr_src, E);
    // agg -> d_out (staging)
    hipLaunchKernelGGL(agg_kernel, dim3((N + 3) / 4), dim3(256), 0, stream, hbuf, csr_src, cursor,
                       counts, dinv, out, N);
    // out = relu(features @ WT2 + agg)
    hipLaunchKernelGGL((gemm_kernel<256, 1>), dim3((N + 127) / 128), dim3(256), 0, stream, features,
                       WT2, (const float*)nullptr, out, (unsigned int*)nullptr, out, N);
}

// Round 4
// 649.733 us; speedup vs baseline: 3.2533x; 1.0290x over previous
//
#include <hip/hip_runtime.h>

#define KAPPA 0.95f

// ---------- bf16 helpers ----------
static __device__ inline unsigned short f2bf(float f) {
    unsigned int u = __float_as_uint(f);
    unsigned int rounding = 0x7fffu + ((u >> 16) & 1u);
    u += rounding;
    return (unsigned short)(u >> 16);
}
static __device__ inline float bflo(unsigned int u) { return __uint_as_float(u << 16); }
static __device__ inline float bfhi(unsigned int u) { return __uint_as_float(u & 0xffff0000u); }

// ---------- 1. proj_norm_inf on W_conv: one BLOCK per row, bitonic in LDS ----------
__global__ __launch_bounds__(128) void proj_kernel(const float* __restrict__ W,
                                                   float* __restrict__ WpT) {
    const int r = blockIdx.x;
    const int tid = threadIdx.x;
    __shared__ float s[128];
    __shared__ float c[128];
    __shared__ int rho_s;

    const float w = W[r * 128 + tid];
    const float a = fabsf(w);
    s[tid] = a;
    if (tid == 0) rho_s = 0;
    __syncthreads();

    for (int k = 2; k <= 128; k <<= 1) {
        for (int j = k >> 1; j > 0; j >>= 1) {
            int ixj = tid ^ j;
            if (ixj > tid) {
                bool up = ((tid & k) == 0);
                float x = s[tid], y = s[ixj];
                if ((x > y) == up) { s[tid] = y; s[ixj] = x; }
            }
            __syncthreads();
        }
    }

    const float u = s[127 - tid];
    c[tid] = u;
    __syncthreads();
    for (int off = 1; off < 128; off <<= 1) {
        float add = (tid >= off) ? c[tid - off] : 0.f;
        __syncthreads();
        c[tid] += add;
        __syncthreads();
    }
    const float rowsum = c[127];
    const float css = c[tid] - KAPPA;
    if (u - css / (float)(tid + 1) > 0.f) atomicAdd(&rho_s, 1);
    __syncthreads();

    float out = w;
    if (rowsum > KAPPA) {
        int rho = max(rho_s, 1);
        float theta = (c[rho - 1] - KAPPA) / (float)rho;
        float m = fmaxf(a - theta, 0.f);
        out = (w > 0.f) ? m : ((w < 0.f) ? -m : 0.f);
    }
    WpT[tid * 128 + r] = out;
}

// ---------- 2. transpose W_mlp ----------
__global__ void transpose_w_kernel(const float* __restrict__ Wm, float* __restrict__ WT2) {
    int idx = blockIdx.x * blockDim.x + threadIdx.x;
    if (idx < 128 * 256) {
        int c = idx >> 8;
        int k = idx & 255;
        WT2[k * 128 + c] = Wm[idx];
    }
}

__global__ void zero_kernel(int* __restrict__ counts, int n) {
    int i = blockIdx.x * blockDim.x + threadIdx.x;
    if (i < n) counts[i] = 0;
}

// ---------- 3a. per-block bucket counts (8 dst-range buckets), atomic-free ----------
__global__ __launch_bounds__(64) void qcount_kernel(const int* __restrict__ dst,
                                                    int* __restrict__ bc, int E, float qscale,
                                                    int chunk, int nbp) {
    const int b = blockIdx.x, lane = threadIdx.x;
    const int i0 = b * chunk;
    const int i1 = min(i0 + chunk, E);
    const int len = max(0, i1 - i0);
    const int nit = (len + 63) >> 6;
    int cnt[8];
#pragma unroll
    for (int k = 0; k < 8; ++k) cnt[k] = 0;
    for (int it = 0; it < nit; ++it) {
        int i = i0 + it * 64 + lane;
        int q = 8;
        if (i < i1) q = min(7, (int)((float)dst[i] * qscale));
#pragma unroll
        for (int k = 0; k < 8; ++k) cnt[k] += (int)__popcll(__ballot(q == k));
    }
    if (lane == 0) {
#pragma unroll
        for (int k = 0; k < 8; ++k) bc[k * nbp + b] = cnt[k];
    }
}

// generic single-block chunked exclusive scan (n <= chunks*1024)
__global__ __launch_bounds__(1024) void scan_kernel(const int* __restrict__ in,
                                                    int* __restrict__ out, int n) {
    __shared__ int tmp[1024];
    __shared__ int carry;
    const int tid = threadIdx.x;
    if (tid == 0) carry = 0;
    __syncthreads();
    for (int base = 0; base < n; base += 1024) {
        int i = base + tid;
        int v = (i < n) ? in[i] : 0;
        tmp[tid] = v;
        __syncthreads();
        int val = v;
        for (int off = 1; off < 1024; off <<= 1) {
            int add = (tid >= off) ? tmp[tid - off] : 0;
            __syncthreads();
            val += add;
            tmp[tid] = val;
            __syncthreads();
        }
        if (i < n) out[i] = carry + val - v;
        int total = tmp[1023];
        __syncthreads();
        if (tid == 0) carry += total;
    }
}

// ---------- 3b. partition edges into 8 dst-range queues, atomic-free ----------
__global__ __launch_bounds__(64) void qpart_kernel(const int* __restrict__ src,
                                                   const int* __restrict__ dst,
                                                   const int* __restrict__ bbase,
                                                   uint2* __restrict__ queue, int E, float qscale,
                                                   int chunk, int nbp) {
    const int b = blockIdx.x, lane = threadIdx.x;
    int base[8];
#pragma unroll
    for (int k = 0; k < 8; ++k) base[k] = bbase[k * nbp + b];
    const int i0 = b * chunk;
    const int i1 = min(i0 + chunk, E);
    const int len = max(0, i1 - i0);
    const int nit = (len + 63) >> 6;
    const unsigned long long ltm = (1ull << lane) - 1ull;
    for (int it = 0; it < nit; ++it) {
        int i = i0 + it * 64 + lane;
        int s = 0, d = 0, q = 8;
        if (i < i1) {
            s = src[i];
            d = dst[i];
            q = min(7, (int)((float)d * qscale));
        }
#pragma unroll
        for (int k = 0; k < 8; ++k) {
            unsigned long long m = __ballot(q == k);
            if (q == k) {
                int rank = (int)__popcll(m & ltm);
                queue[base[k] + rank] = make_uint2((unsigned)s, (unsigned)d);
            }
            base[k] += (int)__popcll(m);
        }
    }
}

// ---------- 3c. XCD-owned count / fill over queues (blockIdx%8 -> XCD) ----------
__global__ __launch_bounds__(256) void countq_kernel(const uint2* __restrict__ queue,
                                                     const int* __restrict__ bbase,
                                                     int* __restrict__ counts, int E, int nbp) {
    const int q = blockIdx.x & 7, j = blockIdx.x >> 3, nj = gridDim.x >> 3;
    const int s = bbase[q * nbp];
    const int e = (q == 7) ? E : bbase[(q + 1) * nbp];
    for (int i = s + j * 256 + threadIdx.x; i < e; i += nj * 256)
        atomicAdd(&counts[queue[i].y], 1);
}

__global__ __launch_bounds__(256) void fillq_kernel(const uint2* __restrict__ queue,
                                                    const int* __restrict__ bbase,
                                                    int* __restrict__ cursor,
                                                    int* __restrict__ csr_src, int E, int nbp) {
    const int q = blockIdx.x & 7, j = blockIdx.x >> 3, nj = gridDim.x >> 3;
    const int s = bbase[q * nbp];
    const int e = (q == 7) ? E : bbase[(q + 1) * nbp];
    for (int i = s + j * 256 + threadIdx.x; i < e; i += nj * 256) {
        uint2 v = queue[i];
        int p = atomicAdd(&cursor[v.y], 1);
        csr_src[p] = (int)v.x;
    }
}

// ---------- 3d. per-node scan: counts -> cursor (exclusive) + dinv ----------
__global__ __launch_bounds__(1024) void scan1_kernel(const int* __restrict__ counts,
                                                     int* __restrict__ partials, int n) {
    __shared__ int tmp[1024];
    int i = blockIdx.x * 1024 + threadIdx.x;
    tmp[threadIdx.x] = (i < n) ? counts[i] : 0;
    __syncthreads();
    for (int off = 512; off > 0; off >>= 1) {
        if (threadIdx.x < off) tmp[threadIdx.x] += tmp[threadIdx.x + off];
        __syncthreads();
    }
    if (threadIdx.x == 0) partials[blockIdx.x] = tmp[0];
}

__global__ __launch_bounds__(1024) void scan2_kernel(int* __restrict__ partials, int nb) {
    __shared__ int tmp[1024];
    const int tid = threadIdx.x;
    int v = (tid < nb) ? partials[tid] : 0;
    tmp[tid] = v;
    __syncthreads();
    int val = v;
    for (int off = 1; off < 1024; off <<= 1) {
        int add = (tid >= off) ? tmp[tid - off] : 0;
        __syncthreads();
        val += add;
        tmp[tid] = val;
        __syncthreads();
    }
    if (tid < nb) partials[tid] = val - v;
}

__global__ __launch_bounds__(1024) void scan3_kernel(const int* __restrict__ counts,
                                                     const int* __restrict__ partials,
                                                     int* __restrict__ cursor,
                                                     float* __restrict__ dinv, int n) {
    __shared__ int tmp[1024];
    const int tid = threadIdx.x;
    int i = blockIdx.x * 1024 + tid;
    int v = (i < n) ? counts[i] : 0;
    tmp[tid] = v;
    __syncthreads();
    int val = v;
    for (int off = 1; off < 1024; off <<= 1) {
        int add = (tid >= off) ? tmp[tid - off] : 0;
        __syncthreads();
        val += add;
        tmp[tid] = val;
        __syncthreads();
    }
    if (i < n) {
        cursor[i] = partials[blockIdx.x] + val - v;
        dinv[i] = rsqrtf((float)(v + 1));
    }
}

// ---------- 4. GEMM: out = X[nrows,KD] @ WT[KD,128] ----------
template <int KD, int MODE>
__global__ __launch_bounds__(256) void gemm_kernel(const float* __restrict__ X,
                                                   const float* __restrict__ WT,
                                                   const float* __restrict__ dinv,
                                                   const float* ADD,
                                                   unsigned int* __restrict__ out_u32,
                                                   float* out_f, int nrows) {
    __shared__ float  ldsX[32][132];
    __shared__ float4 ldsW4[32 * 32];

    const int tid = threadIdx.x;
    const int rg = tid >> 4;
    const int cg = tid & 15;
    const int row0 = blockIdx.x * 128;

    float acc[8][8];
#pragma unroll
    for (int i = 0; i < 8; ++i)
#pragma unroll
        for (int j = 0; j < 8; ++j) acc[i][j] = 0.f;

    const int rload = min(row0 + (tid >> 1), nrows - 1);
    const int kk0 = (tid & 1) * 16;

    for (int k0 = 0; k0 < KD; k0 += 32) {
        __syncthreads();
        {
            const float4* xs =
                reinterpret_cast<const float4*>(&X[(size_t)rload * KD + k0 + kk0]);
            const int r = tid >> 1;
#pragma unroll
            for (int i = 0; i < 4; ++i) {
                float4 v = xs[i];
                int kk = kk0 + i * 4;
                ldsX[kk + 0][r] = v.x;
                ldsX[kk + 1][r] = v.y;
                ldsX[kk + 2][r] = v.z;
                ldsX[kk + 3][r] = v.w;
            }
        }
        {
            const float4* wsrc = reinterpret_cast<const float4*>(&WT[(size_t)k0 * 128]);
#pragma unroll
            for (int i = 0; i < 4; ++i) ldsW4[i * 256 + tid] = wsrc[i * 256 + tid];
        }
        __syncthreads();

#pragma unroll 4
        for (int k = 0; k < 32; ++k) {
            const float4 e0 = *reinterpret_cast<const float4*>(&ldsX[k][rg * 8]);
            const float4 e1 = *reinterpret_cast<const float4*>(&ldsX[k][rg * 8 + 4]);
            const float4 w0 = ldsW4[k * 32 + cg];
            const float4 w1 = ldsW4[k * 32 + 16 + cg];
            const float ev[8] = {e0.x, e0.y, e0.z, e0.w, e1.x, e1.y, e1.z, e1.w};
            const float wv[8] = {w0.x, w0.y, w0.z, w0.w, w1.x, w1.y, w1.z, w1.w};
#pragma unroll
            for (int i = 0; i < 8; ++i)
#pragma unroll
                for (int j = 0; j < 8; ++j) acc[i][j] = fmaf(ev[i], wv[j], acc[i][j]);
        }
    }

#pragma unroll
    for (int i = 0; i < 8; ++i) {
        int r = row0 + rg * 8 + i;
        if (r >= nrows) break;
        if (MODE == 0) {
            float dv = dinv[r];
            unsigned int p01 = (unsigned int)f2bf(acc[i][0] * dv) |
                               ((unsigned int)f2bf(acc[i][1] * dv) << 16);
            unsigned int p23 = (unsigned int)f2bf(acc[i][2] * dv) |
                               ((unsigned int)f2bf(acc[i][3] * dv) << 16);
            unsigned int p45 = (unsigned int)f2bf(acc[i][4] * dv) |
                               ((unsigned int)f2bf(acc[i][5] * dv) << 16);
            unsigned int p67 = (unsigned int)f2bf(acc[i][6] * dv) |
                               ((unsigned int)f2bf(acc[i][7] * dv) << 16);
            uint2 q0 = {p01, p23};
            uint2 q1 = {p45, p67};
            *reinterpret_cast<uint2*>(&out_u32[(size_t)r * 64 + cg * 2]) = q0;
            *reinterpret_cast<uint2*>(&out_u32[(size_t)r * 64 + 32 + cg * 2]) = q1;
        } else {
            const float4 a0 = *reinterpret_cast<const float4*>(&ADD[(size_t)r * 128 + cg * 4]);
            const float4 a1 =
                *reinterpret_cast<const float4*>(&ADD[(size_t)r * 128 + 64 + cg * 4]);
            float4 o0, o1;
            o0.x = fmaxf(acc[i][0] + a0.x, 0.f);
            o0.y = fmaxf(acc[i][1] + a0.y, 0.f);
            o0.z = fmaxf(acc[i][2] + a0.z, 0.f);
            o0.w = fmaxf(acc[i][3] + a0.w, 0.f);
            o1.x = fmaxf(acc[i][4] + a1.x, 0.f);
            o1.y = fmaxf(acc[i][5] + a1.y, 0.f);
            o1.z = fmaxf(acc[i][6] + a1.z, 0.f);
            o1.w = fmaxf(acc[i][7] + a1.w, 0.f);
            *reinterpret_cast<float4*>(&out_f[(size_t)r * 128 + cg * 4]) = o0;
            *reinterpret_cast<float4*>(&out_f[(size_t)r * 128 + 64 + cg * 4]) = o1;
        }
    }
}

// ---------- 5. aggregation ----------
__global__ __launch_bounds__(256) void agg_kernel(const unsigned int* __restrict__ h,
                                                  const int* __restrict__ csr_src,
                                                  const int* __restrict__ cursor,
                                                  const int* __restrict__ counts,
                                                  const float* __restrict__ dinv,
                                                  float* __restrict__ agg, int n) {
    int v = blockIdx.x * 4 + (threadIdx.x >> 6);
    if (v >= n) return;
    const int lane = threadIdx.x & 63;
    const int eg = lane >> 4;
    const int c = lane & 15;
    const int cnt = counts[v];
    const int start = cursor[v] - cnt;

    const uint4* hp = reinterpret_cast<const uint4*>(h);
    float acc[8];
#pragma unroll
    for (int j = 0; j < 8; ++j) acc[j] = 0.f;

    int s_next = (eg < cnt) ? csr_src[start + eg] : -1;
    for (int base = 0; base < cnt; base += 4) {
        int s = s_next;
        int nx = base + 4 + eg;
        s_next = (nx < cnt) ? csr_src[start + nx] : -1;
        if (s >= 0) {
            uint4 val = hp[(size_t)s * 16 + c];
            acc[0] += bflo(val.x); acc[1] += bfhi(val.x);
            acc[2] += bflo(val.y); acc[3] += bfhi(val.y);
            acc[4] += bflo(val.z); acc[5] += bfhi(val.z);
            acc[6] += bflo(val.w); acc[7] += bfhi(val.w);
        }
    }
    if (eg == 0) {
        uint4 val = hp[(size_t)v * 16 + c];
        acc[0] += bflo(val.x); acc[1] += bfhi(val.x);
        acc[2] += bflo(val.y); acc[3] += bfhi(val.y);
        acc[4] += bflo(val.z); acc[5] += bfhi(val.z);
        acc[6] += bflo(val.w); acc[7] += bfhi(val.w);
    }
#pragma unroll
    for (int j = 0; j < 8; ++j) {
        acc[j] += __shfl_xor(acc[j], 16);
        acc[j] += __shfl_xor(acc[j], 32);
    }
    if (eg == 0) {
        float dv = dinv[v];
        float4 o0 = {acc[0] * dv, acc[1] * dv, acc[2] * dv, acc[3] * dv};
        float4 o1 = {acc[4] * dv, acc[5] * dv, acc[6] * dv, acc[7] * dv};
        *reinterpret_cast<float4*>(&agg[(size_t)v * 128 + c * 8]) = o0;
        *reinterpret_cast<float4*>(&agg[(size_t)v * 128 + c * 8 + 4]) = o1;
    }
}

// ---------- launch ----------
extern "C" void kernel_launch(void* const* d_in, const int* in_sizes, int n_in,
                              void* d_out, int out_size, void* d_ws, size_t ws_size,
                              hipStream_t stream) {
    const float* features = (const float*)d_in[0];
    const int*   edge     = (const int*)d_in[1];
    const float* emb      = (const float*)d_in[2];
    const float* Wconv    = (const float*)d_in[3];
    const float* Wmlp     = (const float*)d_in[4];
    float* out = (float*)d_out;

    const int N = in_sizes[0] / 256;
    const int E = in_sizes[1] / 2;
    const int* src = edge;
    const int* dst = edge + E;
    const int NB = (N + 1023) / 1024;
    const int NBP = 1024;                    // partition blocks
    const int chunk = (E + NBP - 1) / NBP;
    const float qscale = 8.0f / (float)N;

    char* ws = (char*)d_ws;
    size_t o = 0;
    auto take = [&](size_t b) {
        size_t cur = o;
        o += (b + 255) & ~(size_t)255;
        return cur;
    };
    float* WpT      = (float*)(ws + take((size_t)128 * 128 * 4));
    float* WT2      = (float*)(ws + take((size_t)256 * 128 * 4));
    int*   counts   = (int*)(ws + take((size_t)N * 4));
    int*   cursor   = (int*)(ws + take((size_t)N * 4));
    float* dinv     = (float*)(ws + take((size_t)N * 4));
    int*   partials = (int*)(ws + take((size_t)(NB + 1) * 4));
    int*   bc       = (int*)(ws + take((size_t)8 * NBP * 4));
    int*   bbase    = (int*)(ws + take((size_t)8 * NBP * 4));
    int*   csr_src  = (int*)(ws + take((size_t)E * 4));
    // queue (E uint2) and hbuf (N*64 u32) share storage: queue is fully
    // consumed by fillq before gemm0 writes hbuf (stream-serialized).
    size_t qbytes = (size_t)E * 8;
    size_t hbytes = (size_t)N * 64 * 4;
    char*  qh     = ws + take(qbytes > hbytes ? qbytes : hbytes);
    uint2*        queue = (uint2*)qh;
    unsigned int* hbuf  = (unsigned int*)qh;
    (void)ws_size; (void)n_in; (void)out_size;

    hipLaunchKernelGGL(proj_kernel, dim3(128), dim3(128), 0, stream, Wconv, WpT);
    hipLaunchKernelGGL(transpose_w_kernel, dim3((128 * 256 + 255) / 256), dim3(256), 0, stream,
                       Wmlp, WT2);
    hipLaunchKernelGGL(zero_kernel, dim3((N + 255) / 256), dim3(256), 0, stream, counts, N);
    // partition edges into 8 dst-range queues (atomic-free)
    hipLaunchKernelGGL(qcount_kernel, dim3(NBP), dim3(64), 0, stream, dst, bc, E, qscale, chunk,
                       NBP);
    hipLaunchKernelGGL(scan_kernel, dim3(1), dim3(1024), 0, stream, bc, bbase, 8 * NBP);
    hipLaunchKernelGGL(qpart_kernel, dim3(NBP), dim3(64), 0, stream, src, dst, bbase, queue, E,
                       qscale, chunk, NBP);
    // XCD-owned degree count over queues
    hipLaunchKernelGGL(countq_kernel, dim3(1024), dim3(256), 0, stream, queue, bbase, counts, E,
                       NBP);
    // per-node exclusive scan -> cursor, dinv
    hipLaunchKernelGGL(scan1_kernel, dim3(NB), dim3(1024), 0, stream, counts, partials, N);
    hipLaunchKernelGGL(scan2_kernel, dim3(1), dim3(1024), 0, stream, partials, NB);
    hipLaunchKernelGGL(scan3_kernel, dim3(NB), dim3(1024), 0, stream, counts, partials, cursor,
                       dinv, N);
    // XCD-owned CSR fill (consumes queue)
    hipLaunchKernelGGL(fillq_kernel, dim3(1024), dim3(256), 0, stream, queue, bbase, cursor,
                       csr_src, E, NBP);
    // h' = bf16( dinv[row] * (emb @ WpT) )  -- overwrites queue storage
    hipLaunchKernelGGL((gemm_kernel<128, 0>), dim3((N + 127) / 128), dim3(256), 0, stream, emb,
                       WpT, dinv, (const float*)nullptr, hbuf, (float*)nullptr, N);
    // agg -> d_out (staging)
    hipLaunchKernelGGL(agg_kernel, dim3((N + 3) / 4), dim3(256), 0, stream, hbuf, csr_src, cursor,
                       counts, dinv, out, N);
    // out = relu(features @ WT2 + agg)
    hipLaunchKernelGGL((gemm_kernel<256, 1>), dim3((N + 127) / 128), dim3(256), 0, stream, features,
                       WT2, (const float*)nullptr, out, (unsigned int*)nullptr, out, N);
}

// Round 5
// 635.845 us; speedup vs baseline: 3.3243x; 1.0218x over previous
//
#include <hip/hip_runtime.h>

#define KAPPA 0.95f

typedef __attribute__((ext_vector_type(8))) short short8;
typedef __attribute__((ext_vector_type(4))) float f32x4;

// ---------- bf16 helpers ----------
static __device__ inline unsigned short f2bf(float f) {
    unsigned int u = __float_as_uint(f);
    unsigned int rounding = 0x7fffu + ((u >> 16) & 1u);
    u += rounding;
    return (unsigned short)(u >> 16);
}
static __device__ inline unsigned int pack2bf(float x, float y) {
    return (unsigned int)f2bf(x) | ((unsigned int)f2bf(y) << 16);
}
static __device__ inline float bflo(unsigned int u) { return __uint_as_float(u << 16); }
static __device__ inline float bfhi(unsigned int u) { return __uint_as_float(u & 0xffff0000u); }

// ---------- 1. proj_norm_inf on W_conv -> bf16 row-major [c][k] ----------
__global__ __launch_bounds__(128) void proj_kernel(const float* __restrict__ W,
                                                   unsigned short* __restrict__ Wp_bf) {
    const int r = blockIdx.x;
    const int tid = threadIdx.x;
    __shared__ float s[128];
    __shared__ float c[128];
    __shared__ int rho_s;

    const float w = W[r * 128 + tid];
    const float a = fabsf(w);
    s[tid] = a;
    if (tid == 0) rho_s = 0;
    __syncthreads();

    for (int k = 2; k <= 128; k <<= 1) {
        for (int j = k >> 1; j > 0; j >>= 1) {
            int ixj = tid ^ j;
            if (ixj > tid) {
                bool up = ((tid & k) == 0);
                float x = s[tid], y = s[ixj];
                if ((x > y) == up) { s[tid] = y; s[ixj] = x; }
            }
            __syncthreads();
        }
    }

    const float u = s[127 - tid];
    c[tid] = u;
    __syncthreads();
    for (int off = 1; off < 128; off <<= 1) {
        float add = (tid >= off) ? c[tid - off] : 0.f;
        __syncthreads();
        c[tid] += add;
        __syncthreads();
    }
    const float rowsum = c[127];
    const float css = c[tid] - KAPPA;
    if (u - css / (float)(tid + 1) > 0.f) atomicAdd(&rho_s, 1);
    __syncthreads();

    float out = w;
    if (rowsum > KAPPA) {
        int rho = max(rho_s, 1);
        float theta = (c[rho - 1] - KAPPA) / (float)rho;
        float m = fmaxf(a - theta, 0.f);
        out = (w > 0.f) ? m : ((w < 0.f) ? -m : 0.f);
    }
    Wp_bf[r * 128 + tid] = f2bf(out);  // row-major [c][k]
}

// ---------- 2. W_mlp f32 -> bf16 (row-major [c][k], same layout) ----------
__global__ void convw_kernel(const float* __restrict__ Wm, unsigned short* __restrict__ Wbf,
                             int n) {
    int i = blockIdx.x * blockDim.x + threadIdx.x;
    if (i < n) Wbf[i] = f2bf(Wm[i]);
}

__global__ void zero_kernel(int* __restrict__ counts, int n) {
    int i = blockIdx.x * blockDim.x + threadIdx.x;
    if (i < n) counts[i] = 0;
}

// ---------- 3a. per-block bucket counts (8 dst-range buckets), atomic-free ----------
__global__ __launch_bounds__(64) void qcount_kernel(const int* __restrict__ dst,
                                                    int* __restrict__ bc, int E, float qscale,
                                                    int chunk, int nbp) {
    const int b = blockIdx.x, lane = threadIdx.x;
    const int i0 = b * chunk;
    const int i1 = min(i0 + chunk, E);
    const int len = max(0, i1 - i0);
    const int nit = (len + 63) >> 6;
    int cnt[8];
#pragma unroll
    for (int k = 0; k < 8; ++k) cnt[k] = 0;
    for (int it = 0; it < nit; ++it) {
        int i = i0 + it * 64 + lane;
        int q = 8;
        if (i < i1) q = min(7, (int)((float)dst[i] * qscale));
#pragma unroll
        for (int k = 0; k < 8; ++k) cnt[k] += (int)__popcll(__ballot(q == k));
    }
    if (lane == 0) {
#pragma unroll
        for (int k = 0; k < 8; ++k) bc[k * nbp + b] = cnt[k];
    }
}

// generic single-block chunked exclusive scan
__global__ __launch_bounds__(1024) void scan_kernel(const int* __restrict__ in,
                                                    int* __restrict__ out, int n) {
    __shared__ int tmp[1024];
    __shared__ int carry;
    const int tid = threadIdx.x;
    if (tid == 0) carry = 0;
    __syncthreads();
    for (int base = 0; base < n; base += 1024) {
        int i = base + tid;
        int v = (i < n) ? in[i] : 0;
        tmp[tid] = v;
        __syncthreads();
        int val = v;
        for (int off = 1; off < 1024; off <<= 1) {
            int add = (tid >= off) ? tmp[tid - off] : 0;
            __syncthreads();
            val += add;
            tmp[tid] = val;
            __syncthreads();
        }
        if (i < n) out[i] = carry + val - v;
        int total = tmp[1023];
        __syncthreads();
        if (tid == 0) carry += total;
    }
}

// ---------- 3b. partition edges into 8 dst-range queues, atomic-free ----------
__global__ __launch_bounds__(64) void qpart_kernel(const int* __restrict__ src,
                                                   const int* __restrict__ dst,
                                                   const int* __restrict__ bbase,
                                                   uint2* __restrict__ queue, int E, float qscale,
                                                   int chunk, int nbp) {
    const int b = blockIdx.x, lane = threadIdx.x;
    int base[8];
#pragma unroll
    for (int k = 0; k < 8; ++k) base[k] = bbase[k * nbp + b];
    const int i0 = b * chunk;
    const int i1 = min(i0 + chunk, E);
    const int len = max(0, i1 - i0);
    const int nit = (len + 63) >> 6;
    const unsigned long long ltm = (1ull << lane) - 1ull;
    for (int it = 0; it < nit; ++it) {
        int i = i0 + it * 64 + lane;
        int s = 0, d = 0, q = 8;
        if (i < i1) {
            s = src[i];
            d = dst[i];
            q = min(7, (int)((float)d * qscale));
        }
#pragma unroll
        for (int k = 0; k < 8; ++k) {
            unsigned long long m = __ballot(q == k);
            if (q == k) {
                int rank = (int)__popcll(m & ltm);
                queue[base[k] + rank] = make_uint2((unsigned)s, (unsigned)d);
            }
            base[k] += (int)__popcll(m);
        }
    }
}

// ---------- 3c. XCD-owned count / fill over queues; nt loads keep queue out of L2 ----------
__global__ __launch_bounds__(256) void countq_kernel(const uint2* __restrict__ queue,
                                                     const int* __restrict__ bbase,
                                                     int* __restrict__ counts, int E, int nbp) {
    const int q = blockIdx.x & 7, j = blockIdx.x >> 3, nj = gridDim.x >> 3;
    const int s = bbase[q * nbp];
    const int e = (q == 7) ? E : bbase[(q + 1) * nbp];
    const unsigned long long* qp = reinterpret_cast<const unsigned long long*>(queue);
    for (int i = s + j * 256 + threadIdx.x; i < e; i += nj * 256) {
        unsigned long long raw = __builtin_nontemporal_load(qp + i);
        atomicAdd(&counts[(unsigned int)(raw >> 32)], 1);
    }
}

__global__ __launch_bounds__(256) void fillq_kernel(const uint2* __restrict__ queue,
                                                    const int* __restrict__ bbase,
                                                    int* __restrict__ cursor,
                                                    int* __restrict__ csr_src, int E, int nbp) {
    const int q = blockIdx.x & 7, j = blockIdx.x >> 3, nj = gridDim.x >> 3;
    const int s = bbase[q * nbp];
    const int e = (q == 7) ? E : bbase[(q + 1) * nbp];
    const unsigned long long* qp = reinterpret_cast<const unsigned long long*>(queue);
    for (int i = s + j * 256 + threadIdx.x; i < e; i += nj * 256) {
        unsigned long long raw = __builtin_nontemporal_load(qp + i);
        int p = atomicAdd(&cursor[(unsigned int)(raw >> 32)], 1);
        csr_src[p] = (int)(unsigned int)raw;
    }
}

// ---------- 3d. per-node scan: counts -> cursor (exclusive) + dinv ----------
__global__ __launch_bounds__(1024) void scan1_kernel(const int* __restrict__ counts,
                                                     int* __restrict__ partials, int n) {
    __shared__ int tmp[1024];
    int i = blockIdx.x * 1024 + threadIdx.x;
    tmp[threadIdx.x] = (i < n) ? counts[i] : 0;
    __syncthreads();
    for (int off = 512; off > 0; off >>= 1) {
        if (threadIdx.x < off) tmp[threadIdx.x] += tmp[threadIdx.x + off];
        __syncthreads();
    }
    if (threadIdx.x == 0) partials[blockIdx.x] = tmp[0];
}

__global__ __launch_bounds__(1024) void scan2_kernel(int* __restrict__ partials, int nb) {
    __shared__ int tmp[1024];
    const int tid = threadIdx.x;
    int v = (tid < nb) ? partials[tid] : 0;
    tmp[tid] = v;
    __syncthreads();
    int val = v;
    for (int off = 1; off < 1024; off <<= 1) {
        int add = (tid >= off) ? tmp[tid - off] : 0;
        __syncthreads();
        val += add;
        tmp[tid] = val;
        __syncthreads();
    }
    if (tid < nb) partials[tid] = val - v;
}

__global__ __launch_bounds__(1024) void scan3_kernel(const int* __restrict__ counts,
                                                     const int* __restrict__ partials,
                                                     int* __restrict__ cursor,
                                                     float* __restrict__ dinv, int n) {
    __shared__ int tmp[1024];
    const int tid = threadIdx.x;
    int i = blockIdx.x * 1024 + tid;
    int v = (i < n) ? counts[i] : 0;
    tmp[tid] = v;
    __syncthreads();
    int val = v;
    for (int off = 1; off < 1024; off <<= 1) {
        int add = (tid >= off) ? tmp[tid - off] : 0;
        __syncthreads();
        val += add;
        tmp[tid] = val;
        __syncthreads();
    }
    if (i < n) {
        cursor[i] = partials[blockIdx.x] + val - v;
        dinv[i] = rsqrtf((float)(v + 1));
    }
}

// ---------- 4. MFMA GEMM: out = X[nrows,KD](f32) @ Wbf[c][k](bf16).T ----------
// block = 256 thr = 4 waves; 128 rows x 128 cols per block; wave = 32 rows.
// MODE 0: out_bf[r][c] = bf16(dinv[r] * acc)     MODE 1: out_f = relu(acc + ADD)
template <int KD, int MODE>
__global__ __launch_bounds__(256) void gemm_mfma(const float* __restrict__ X,
                                                 const unsigned short* __restrict__ Wbf,
                                                 const float* __restrict__ dinv,
                                                 const float* ADD,
                                                 unsigned short* __restrict__ out_bf,
                                                 float* out_f, int nrows) {
    __shared__ __align__(16) unsigned short ldsX[128 * 40];  // [row][40], pad 8
    const int tid = threadIdx.x;
    const int w = tid >> 6;
    const int l = tid & 63;
    const int l16 = l & 15;
    const int kg = l >> 4;  // 0..3
    const int row0 = blockIdx.x * 128;

    f32x4 acc[2][8];
#pragma unroll
    for (int i = 0; i < 2; ++i)
#pragma unroll
        for (int j = 0; j < 8; ++j) acc[i][j] = (f32x4)(0.f);

    const int srow = tid >> 1;  // staging row 0..127
    const int rload = min(row0 + srow, nrows - 1);
    const int kk0 = (tid & 1) * 16;
    const float* xrow = X + (size_t)rload * KD + kk0;

    for (int k0 = 0; k0 < KD; k0 += 32) {
        __syncthreads();
        {
            const float4* xs = reinterpret_cast<const float4*>(xrow + k0);
            float4 v0 = xs[0], v1 = xs[1], v2 = xs[2], v3 = xs[3];
            uint4 pa, pb;
            pa.x = pack2bf(v0.x, v0.y); pa.y = pack2bf(v0.z, v0.w);
            pa.z = pack2bf(v1.x, v1.y); pa.w = pack2bf(v1.z, v1.w);
            pb.x = pack2bf(v2.x, v2.y); pb.y = pack2bf(v2.z, v2.w);
            pb.z = pack2bf(v3.x, v3.y); pb.w = pack2bf(v3.z, v3.w);
            *reinterpret_cast<uint4*>(&ldsX[srow * 40 + kk0]) = pa;
            *reinterpret_cast<uint4*>(&ldsX[srow * 40 + kk0 + 8]) = pb;
        }
        __syncthreads();

        short8 a0 = *reinterpret_cast<const short8*>(&ldsX[(w * 32 + l16) * 40 + kg * 8]);
        short8 a1 = *reinterpret_cast<const short8*>(&ldsX[(w * 32 + 16 + l16) * 40 + kg * 8]);
#pragma unroll
        for (int ct = 0; ct < 8; ++ct) {
            short8 b = *reinterpret_cast<const short8*>(
                &Wbf[(size_t)(ct * 16 + l16) * KD + k0 + kg * 8]);
            acc[0][ct] = __builtin_amdgcn_mfma_f32_16x16x32_bf16(a0, b, acc[0][ct], 0, 0, 0);
            acc[1][ct] = __builtin_amdgcn_mfma_f32_16x16x32_bf16(a1, b, acc[1][ct], 0, 0, 0);
        }
    }

#pragma unroll
    for (int rt = 0; rt < 2; ++rt) {
        const int rbase = row0 + w * 32 + rt * 16 + kg * 4;
        float dv[4];
        if (MODE == 0) {
#pragma unroll
            for (int reg = 0; reg < 4; ++reg)
                dv[reg] = (rbase + reg < nrows) ? dinv[rbase + reg] : 0.f;
        }
#pragma unroll
        for (int ct = 0; ct < 8; ++ct) {
            const int col = ct * 16 + l16;
            f32x4 d = acc[rt][ct];
#pragma unroll
            for (int reg = 0; reg < 4; ++reg) {
                int r = rbase + reg;
                if (r < nrows) {
                    if (MODE == 0) {
                        out_bf[(size_t)r * 128 + col] = f2bf(d[reg] * dv[reg]);
                    } else {
                        float add = ADD[(size_t)r * 128 + col];
                        out_f[(size_t)r * 128 + col] = fmaxf(d[reg] + add, 0.f);
                    }
                }
            }
        }
    }
}

// ---------- 5. aggregation ----------
__global__ __launch_bounds__(256) void agg_kernel(const unsigned int* __restrict__ h,
                                                  const int* __restrict__ csr_src,
                                                  const int* __restrict__ cursor,
                                                  const int* __restrict__ counts,
                                                  const float* __restrict__ dinv,
                                                  float* __restrict__ agg, int n) {
    int v = blockIdx.x * 4 + (threadIdx.x >> 6);
    if (v >= n) return;
    const int lane = threadIdx.x & 63;
    const int eg = lane >> 4;
    const int c = lane & 15;
    const int cnt = counts[v];
    const int start = cursor[v] - cnt;

    const uint4* hp = reinterpret_cast<const uint4*>(h);
    float acc[8];
#pragma unroll
    for (int j = 0; j < 8; ++j) acc[j] = 0.f;

    int s_next = (eg < cnt) ? csr_src[start + eg] : -1;
    for (int base = 0; base < cnt; base += 4) {
        int s = s_next;
        int nx = base + 4 + eg;
        s_next = (nx < cnt) ? csr_src[start + nx] : -1;
        if (s >= 0) {
            uint4 val = hp[(size_t)s * 16 + c];
            acc[0] += bflo(val.x); acc[1] += bfhi(val.x);
            acc[2] += bflo(val.y); acc[3] += bfhi(val.y);
            acc[4] += bflo(val.z); acc[5] += bfhi(val.z);
            acc[6] += bflo(val.w); acc[7] += bfhi(val.w);
        }
    }
    if (eg == 0) {
        uint4 val = hp[(size_t)v * 16 + c];
        acc[0] += bflo(val.x); acc[1] += bfhi(val.x);
        acc[2] += bflo(val.y); acc[3] += bfhi(val.y);
        acc[4] += bflo(val.z); acc[5] += bfhi(val.z);
        acc[6] += bflo(val.w); acc[7] += bfhi(val.w);
    }
#pragma unroll
    for (int j = 0; j < 8; ++j) {
        acc[j] += __shfl_xor(acc[j], 16);
        acc[j] += __shfl_xor(acc[j], 32);
    }
    if (eg == 0) {
        float dv = dinv[v];
        float4 o0 = {acc[0] * dv, acc[1] * dv, acc[2] * dv, acc[3] * dv};
        float4 o1 = {acc[4] * dv, acc[5] * dv, acc[6] * dv, acc[7] * dv};
        *reinterpret_cast<float4*>(&agg[(size_t)v * 128 + c * 8]) = o0;
        *reinterpret_cast<float4*>(&agg[(size_t)v * 128 + c * 8 + 4]) = o1;
    }
}

// ---------- launch ----------
extern "C" void kernel_launch(void* const* d_in, const int* in_sizes, int n_in,
                              void* d_out, int out_size, void* d_ws, size_t ws_size,
                              hipStream_t stream) {
    const float* features = (const float*)d_in[0];
    const int*   edge     = (const int*)d_in[1];
    const float* emb      = (const float*)d_in[2];
    const float* Wconv    = (const float*)d_in[3];
    const float* Wmlp     = (const float*)d_in[4];
    float* out = (float*)d_out;

    const int N = in_sizes[0] / 256;
    const int E = in_sizes[1] / 2;
    const int* src = edge;
    const int* dst = edge + E;
    const int NB = (N + 1023) / 1024;
    const int NBP = 1024;
    const int chunk = (E + NBP - 1) / NBP;
    const float qscale = 8.0f / (float)N;

    char* ws = (char*)d_ws;
    size_t o = 0;
    auto take = [&](size_t b) {
        size_t cur = o;
        o += (b + 255) & ~(size_t)255;
        return cur;
    };
    unsigned short* Wp_bf   = (unsigned short*)(ws + take((size_t)128 * 128 * 2));
    unsigned short* Wm_bf   = (unsigned short*)(ws + take((size_t)128 * 256 * 2));
    int*            counts  = (int*)(ws + take((size_t)N * 4));
    int*            cursor  = (int*)(ws + take((size_t)N * 4));
    float*          dinv    = (float*)(ws + take((size_t)N * 4));
    int*            partials= (int*)(ws + take((size_t)(NB + 1) * 4));
    int*            bc      = (int*)(ws + take((size_t)8 * NBP * 4));
    int*            bbase   = (int*)(ws + take((size_t)8 * NBP * 4));
    int*            csr_src = (int*)(ws + take((size_t)E * 4));
    size_t qbytes = (size_t)E * 8;
    size_t hbytes = (size_t)N * 128 * 2;
    char*  qh     = ws + take(qbytes > hbytes ? qbytes : hbytes);
    uint2*          queue = (uint2*)qh;
    unsigned short* hbuf  = (unsigned short*)qh;
    (void)ws_size; (void)n_in; (void)out_size;

    hipLaunchKernelGGL(proj_kernel, dim3(128), dim3(128), 0, stream, Wconv, Wp_bf);
    hipLaunchKernelGGL(convw_kernel, dim3((128 * 256 + 255) / 256), dim3(256), 0, stream, Wmlp,
                       Wm_bf, 128 * 256);
    hipLaunchKernelGGL(zero_kernel, dim3((N + 255) / 256), dim3(256), 0, stream, counts, N);
    hipLaunchKernelGGL(qcount_kernel, dim3(NBP), dim3(64), 0, stream, dst, bc, E, qscale, chunk,
                       NBP);
    hipLaunchKernelGGL(scan_kernel, dim3(1), dim3(1024), 0, stream, bc, bbase, 8 * NBP);
    hipLaunchKernelGGL(qpart_kernel, dim3(NBP), dim3(64), 0, stream, src, dst, bbase, queue, E,
                       qscale, chunk, NBP);
    hipLaunchKernelGGL(countq_kernel, dim3(1024), dim3(256), 0, stream, queue, bbase, counts, E,
                       NBP);
    hipLaunchKernelGGL(scan1_kernel, dim3(NB), dim3(1024), 0, stream, counts, partials, N);
    hipLaunchKernelGGL(scan2_kernel, dim3(1), dim3(1024), 0, stream, partials, NB);
    hipLaunchKernelGGL(scan3_kernel, dim3(NB), dim3(1024), 0, stream, counts, partials, cursor,
                       dinv, N);
    hipLaunchKernelGGL(fillq_kernel, dim3(1024), dim3(256), 0, stream, queue, bbase, cursor,
                       csr_src, E, NBP);
    // h' = bf16( dinv[row] * (emb @ Wp.T) )  -- overwrites queue storage
    hipLaunchKernelGGL((gemm_mfma<128, 0>), dim3((N + 127) / 128), dim3(256), 0, stream, emb,
                       Wp_bf, dinv, (const float*)nullptr, hbuf, (float*)nullptr, N);
    hipLaunchKernelGGL(agg_kernel, dim3((N + 3) / 4), dim3(256), 0, stream,
                       (const unsigned int*)hbuf, csr_src, cursor, counts, dinv, out, N);
    // out = relu(features @ Wmlp.T + agg)
    hipLaunchKernelGGL((gemm_mfma<256, 1>), dim3((N + 127) / 128), dim3(256), 0, stream, features,
                       Wm_bf, (const float*)nullptr, out, (unsigned short*)nullptr, out, N);
}